// Round 5
// baseline (474.824 us; speedup 1.0000x reference)
//
#include <hip/hip_runtime.h>

// out[b,m,p] (B=512, OUT=400):
//   = x[b,m,p]   for m<256 && p<256   (eye = identity embedding)
//   = 1.0f       for m==p >= 256      (add = diag(0*256, 1*144))
//   = 0.0f       otherwise
// One 64B chunk (4 float4) per thread; chunk never crosses a row (4 | 100).
// Contiguous NT writes, NT x reads, no eye/add reads.
// Traffic: 134.2MB read + 327.7MB write.

typedef float f32x4 __attribute__((ext_vector_type(4)));

constexpr unsigned B   = 512;
constexpr unsigned IN  = 256;
constexpr unsigned OUT = 400;
constexpr unsigned ROW4     = OUT / 4;             // 100 f4 per out row
constexpr unsigned TOTAL_F4 = B * OUT * ROW4;      // 20,480,000
constexpr unsigned CHUNKS   = TOTAL_F4 / 4;        // 5,120,000 threads

__global__ __launch_bounds__(256) void spd_chunk4(
    const f32x4* __restrict__ x4, f32x4* __restrict__ out4)
{
    const unsigned t  = blockIdx.x * 256u + threadIdx.x;
    const unsigned i0 = t * 4u;                 // first f4 of this 64B chunk
    unsigned bm = i0 / 100u;                    // magic mulhi
    unsigned p4 = i0 - bm * 100u;               // multiple of 4, <100
    unsigned b  = bm / 400u;                    // magic mulhi
    unsigned m  = bm - b * 400u;

    if (m < IN && p4 < (IN / 4)) {
        // whole chunk inside the x-copy block (p4 in {0,4,...,60})
        const f32x4* src = &x4[(b << 14) + (m << 6) + p4];
        f32x4 v0 = __builtin_nontemporal_load(src + 0);
        f32x4 v1 = __builtin_nontemporal_load(src + 1);
        f32x4 v2 = __builtin_nontemporal_load(src + 2);
        f32x4 v3 = __builtin_nontemporal_load(src + 3);
        __builtin_nontemporal_store(v0, &out4[i0 + 0]);
        __builtin_nontemporal_store(v1, &out4[i0 + 1]);
        __builtin_nontemporal_store(v2, &out4[i0 + 2]);
        __builtin_nontemporal_store(v3, &out4[i0 + 3]);
    } else {
        // zero fill + possible diagonal one (rows m>=256 only)
        const bool diag_row = (m >= IN);
        const unsigned base_p = p4 * 4u;        // element index of chunk start
#pragma unroll
        for (unsigned j = 0; j < 4; ++j) {
            f32x4 v;
            // element p = base_p + j*4 + e ; one iff diag_row && p == m
            v.x = (diag_row && base_p + j * 4u + 0u == m) ? 1.0f : 0.0f;
            v.y = (diag_row && base_p + j * 4u + 1u == m) ? 1.0f : 0.0f;
            v.z = (diag_row && base_p + j * 4u + 2u == m) ? 1.0f : 0.0f;
            v.w = (diag_row && base_p + j * 4u + 3u == m) ? 1.0f : 0.0f;
            __builtin_nontemporal_store(v, &out4[i0 + j]);
        }
    }
}

extern "C" void kernel_launch(void* const* d_in, const int* in_sizes, int n_in,
                              void* d_out, int out_size, void* d_ws, size_t ws_size,
                              hipStream_t stream)
{
    const f32x4* x4 = (const f32x4*)d_in[0];  // [B, IN, IN]
    f32x4* out4 = (f32x4*)d_out;              // [B, OUT, OUT]

    spd_chunk4<<<CHUNKS / 256, 256, 0, stream>>>(x4, out4);
}

// Round 6
// 85.323 us; speedup vs baseline: 5.5650x; 5.5650x over previous
//
#include <hip/hip_runtime.h>

// out[b,m,p] (B=512, OUT=400):
//   = x[b,m,p]   for m<256 && p<256   (eye = identity embedding)
//   = 1.0f       for m==p >= 256      (add = diag(0*256, 1*144))
//   = 0.0f       otherwise
// Lane-contiguous (coalesced) NT accesses; 4 f4 per thread via WAVE-STRIDE
// unroll (block*1024 + j*256 + tid), so every instruction is a contiguous
// 1KB wave access, but each thread has 4 independent loads in flight.
// Traffic: 134.2MB read + 327.7MB write.

typedef float f32x4 __attribute__((ext_vector_type(4)));

constexpr unsigned B   = 512;
constexpr unsigned IN  = 256;
constexpr unsigned OUT = 400;
constexpr unsigned ROW4     = OUT / 4;             // 100 f4 per out row
constexpr unsigned TOTAL_F4 = B * OUT * ROW4;      // 20,480,000 = 20000*1024
constexpr unsigned PER_BLK  = 1024;                // 256 threads x 4 f4

__global__ __launch_bounds__(256) void spd_unroll4(
    const f32x4* __restrict__ x4, f32x4* __restrict__ out4)
{
    const unsigned base = blockIdx.x * PER_BLK + threadIdx.x;

    f32x4 v0, v1, v2, v3;   // static names, stays in VGPRs
#pragma unroll
    for (unsigned j = 0; j < 4; ++j) {
        const unsigned i = base + j * 256u;
        unsigned bm = i / 100u;              // magic mulhi
        unsigned p4 = i - bm * 100u;
        unsigned b  = bm / 400u;             // magic mulhi
        unsigned m  = bm - b * 400u;

        f32x4 v;
        if (m < IN && p4 < (IN / 4)) {
            v = __builtin_nontemporal_load(&x4[(b << 14) + (m << 6) + p4]);
        } else {
            v = (f32x4){0.f, 0.f, 0.f, 0.f};
            if (m >= IN && p4 == (m >> 2)) {
                v[m & 3u] = 1.0f;            // diagonal one (compile-time lane idx after unroll? m&3 is runtime but scalar insert)
            }
        }
        if (j == 0) v0 = v; else if (j == 1) v1 = v;
        else if (j == 2) v2 = v; else v3 = v;
    }

    __builtin_nontemporal_store(v0, &out4[base + 0u * 256u]);
    __builtin_nontemporal_store(v1, &out4[base + 1u * 256u]);
    __builtin_nontemporal_store(v2, &out4[base + 2u * 256u]);
    __builtin_nontemporal_store(v3, &out4[base + 3u * 256u]);
}

extern "C" void kernel_launch(void* const* d_in, const int* in_sizes, int n_in,
                              void* d_out, int out_size, void* d_ws, size_t ws_size,
                              hipStream_t stream)
{
    const f32x4* x4 = (const f32x4*)d_in[0];  // [B, IN, IN]
    f32x4* out4 = (f32x4*)d_out;              // [B, OUT, OUT]

    spd_unroll4<<<TOTAL_F4 / PER_BLK, 256, 0, stream>>>(x4, out4);
}